// Round 1
// baseline (3591.565 us; speedup 1.0000x reference)
//
#include <hip/hip_runtime.h>
#include <hip/hip_bf16.h>
#include <math.h>

#define NEGF (-3.402823466e38f)

// ---------------- prep: pack Wq/Wk/Wv [N,H,D,DK] -> WT [N][D][768] ----------------
// col = ty*256 + h*32 + e   (ty: 0=q 1=k 2=v)
__global__ void prep_wqkv_kernel(const float* __restrict__ Wq,
                                 const float* __restrict__ Wk,
                                 const float* __restrict__ Wv,
                                 float* __restrict__ WT) {
  int idx = blockIdx.x * 256 + threadIdx.x;
  const int total = 4 * 256 * 768;
  if (idx >= total) return;
  int col = idx % 768;
  int d   = (idx / 768) % 256;
  int n   = idx / (768 * 256);
  int ty  = col >> 8;
  int h   = (col >> 5) & 7;
  int e   = col & 31;
  const float* W = (ty == 0) ? Wq : (ty == 1) ? Wk : Wv;
  WT[idx] = W[(((size_t)n * 8 + h) * 256 + d) * 32 + e];
}

// ---------------- generic f32 GEMM, 128x64 tile, BK=32, 256 threads ----------------
// EP: 0 = none, 1 = gelu(acc + bias), 2 = (acc [+ bias] + res) * 0.5
template <int EP>
__global__ __launch_bounds__(256)
void gemm_f32_kernel(const float* __restrict__ A, const float* __restrict__ B,
                     float* __restrict__ C, const float* __restrict__ bias,
                     const float* __restrict__ res, int M, int N, int K) {
  __shared__ float As[128][36];   // pitch 36: 16B-aligned rows, conflict-free frag reads
  __shared__ float Bs[32][64];
  const int t  = threadIdx.x;
  const int r0 = blockIdx.x * 128;
  const int n0 = blockIdx.y * 64;
  const int tc = t & 15;   // 16 col-groups * 4 cols
  const int tr = t >> 4;   // 16 row-groups; rows tr + 16*j

  float acc[8][4];
  #pragma unroll
  for (int j = 0; j < 8; ++j)
    #pragma unroll
    for (int c = 0; c < 4; ++c) acc[j][c] = 0.f;

  for (int k0 = 0; k0 < K; k0 += 32) {
    __syncthreads();
    // stage A tile [128 rows][32 k] : 1024 float4, 4 per thread
    #pragma unroll
    for (int i = 0; i < 4; ++i) {
      int e = t + 256 * i;
      int row = e >> 3, kq = e & 7;
      float4 f = *(const float4*)(A + (size_t)(r0 + row) * K + k0 + kq * 4);
      *(float4*)&As[row][kq * 4] = f;
    }
    // stage B tile [32 k][64 cols] : 512 float4, 2 per thread
    #pragma unroll
    for (int i = 0; i < 2; ++i) {
      int e = t + 256 * i;
      int row = e >> 4, cq = e & 15;
      float4 f = *(const float4*)(B + (size_t)(k0 + row) * N + n0 + cq * 4);
      *(float4*)&Bs[row][cq * 4] = f;
    }
    __syncthreads();
    #pragma unroll
    for (int kk = 0; kk < 32; ++kk) {
      float bfrag[4];
      *(float4*)bfrag = *(const float4*)&Bs[kk][tc * 4];
      float afrag[8];
      #pragma unroll
      for (int j = 0; j < 8; ++j) afrag[j] = As[tr + 16 * j][kk];
      #pragma unroll
      for (int j = 0; j < 8; ++j)
        #pragma unroll
        for (int c = 0; c < 4; ++c) acc[j][c] += afrag[j] * bfrag[c];
    }
  }

  #pragma unroll
  for (int j = 0; j < 8; ++j) {
    int row = r0 + tr + 16 * j;
    size_t off = (size_t)row * N + n0 + tc * 4;
    float4 v;
    float* pv = (float*)&v;
    #pragma unroll
    for (int c = 0; c < 4; ++c) {
      float x = acc[j][c];
      if (EP == 1) {
        x += bias[n0 + tc * 4 + c];
        x = 0.5f * x * (1.f + erff(x * 0.70710678118654752f));
      } else if (EP == 2) {
        if (bias) x += bias[n0 + tc * 4 + c];
        x = (x + res[off + c]) * 0.5f;
      }
      pv[c] = x;
    }
    *(float4*)(C + off) = v;
  }
}

// ---------------- fused flash attention ----------------
// qkv layout: [B*L][768], q at col 0 + h*32, k at 256 + h*32, v at 512 + h*32
// out: [B*L][256] with col = h*32 + e
// grid: b*64 + h*8 + qblk  (256 WGs), 256 threads = 1 query each
__global__ __launch_bounds__(256)
void attn_kernel(const float* __restrict__ qkv, const float* __restrict__ mask,
                 float* __restrict__ out) {
  __shared__ float Klds[64][32];
  __shared__ float Vlds[64][32];
  __shared__ float mlds[64];
  const int t    = threadIdx.x;
  const int wg   = blockIdx.x;
  const int qblk = wg & 7;
  const int h    = (wg >> 3) & 7;
  const int b    = wg >> 6;
  const int qrow = qblk * 256 + t;

  const float* qp = qkv + ((size_t)(b * 2048 + qrow)) * 768 + h * 32;
  float qv[32];
  #pragma unroll
  for (int i = 0; i < 8; ++i) {
    float4 f = *(const float4*)(qp + 4 * i);
    qv[4*i] = f.x; qv[4*i+1] = f.y; qv[4*i+2] = f.z; qv[4*i+3] = f.w;
  }
  const float mq = mask[b * 2048 + qrow];

  float m = -INFINITY, l = 0.f;
  float o[32];
  #pragma unroll
  for (int i = 0; i < 32; ++i) o[i] = 0.f;

  for (int j0 = 0; j0 < 2048; j0 += 64) {
    __syncthreads();
    #pragma unroll
    for (int it = 0; it < 2; ++it) {
      int e = t + 256 * it;
      int row = e >> 3, q4 = e & 7;
      size_t base = ((size_t)(b * 2048 + j0 + row)) * 768 + h * 32 + q4 * 4;
      *(float4*)&Klds[row][q4 * 4] = *(const float4*)(qkv + base + 256);
      *(float4*)&Vlds[row][q4 * 4] = *(const float4*)(qkv + base + 512);
    }
    if (t < 64) mlds[t] = mask[b * 2048 + j0 + t];
    __syncthreads();

    #pragma unroll 2
    for (int j = 0; j < 64; ++j) {
      const float4* kj = (const float4*)Klds[j];
      float s0 = 0.f, s1 = 0.f, s2 = 0.f, s3 = 0.f;
      #pragma unroll
      for (int i = 0; i < 8; ++i) {
        float4 kf = kj[i];
        s0 += qv[4*i+0] * kf.x;
        s1 += qv[4*i+1] * kf.y;
        s2 += qv[4*i+2] * kf.z;
        s3 += qv[4*i+3] * kf.w;
      }
      float s  = (s0 + s1) + (s2 + s3);
      float sm = (mq * mlds[j] != 0.f) ? s : NEGF;   // exact replica of +finfo.min in f32
      const float* vj = &Vlds[j][0];
      if (sm > m) {
        float r = __expf(m - sm);   // m=-inf first iter -> r=0, l=1, o=v
        l = l * r + 1.f;
        #pragma unroll
        for (int i = 0; i < 32; ++i) o[i] = o[i] * r + vj[i];
        m = sm;
      } else {
        float p = __expf(sm - m);   // all-NEG rows: p=1 each -> uniform (matches ref)
        l += p;
        #pragma unroll
        for (int i = 0; i < 32; ++i) o[i] += p * vj[i];
      }
    }
  }

  const float inv = 1.f / l;
  float* op = out + ((size_t)(b * 2048 + qrow)) * 256 + h * 32;
  #pragma unroll
  for (int i = 0; i < 8; ++i) {
    float4 f;
    f.x = o[4*i+0] * inv; f.y = o[4*i+1] * inv;
    f.z = o[4*i+2] * inv; f.w = o[4*i+3] * inv;
    *(float4*)(op + 4 * i) = f;
  }
}

// ---------------- launch ----------------
extern "C" void kernel_launch(void* const* d_in, const int* in_sizes, int n_in,
                              void* d_out, int out_size, void* d_ws, size_t ws_size,
                              hipStream_t stream) {
  const float* x    = (const float*)d_in[0];
  const float* mask = (const float*)d_in[1];
  const float* Wq   = (const float*)d_in[2];
  const float* Wk   = (const float*)d_in[3];
  const float* Wv   = (const float*)d_in[4];
  const float* Wo   = (const float*)d_in[5];
  const float* W1   = (const float*)d_in[6];
  const float* b1   = (const float*)d_in[7];
  const float* W2   = (const float*)d_in[8];
  const float* b2   = (const float*)d_in[9];
  float* outp = (float*)d_out;

  char* ws = (char*)d_ws;
  float* xc     = (float*)(ws);                               // 8 MiB  [8192][256]
  float* qkvb   = (float*)(ws + ((size_t)8  << 20));          // 24 MiB [8192][768]
  float* ffb    = qkvb;                                       // reuse (disjoint in time)
  float* attno  = (float*)(ws + ((size_t)32 << 20));          // 8 MiB  [8192][256]
  float* wqkvT  = (float*)(ws + ((size_t)40 << 20));          // 3 MiB  [4][256][768]

  // xc = x
  hipMemcpyAsync(xc, x, (size_t)8192 * 256 * sizeof(float),
                 hipMemcpyDeviceToDevice, stream);
  // pack qkv weights
  prep_wqkv_kernel<<<3072, 256, 0, stream>>>(Wq, Wk, Wv, wqkvT);

  for (int n = 0; n < 4; ++n) {
    // 1) qkv = xc @ WqkvT[n]          [8192,768]
    gemm_f32_kernel<0><<<dim3(64, 12), 256, 0, stream>>>(
        xc, wqkvT + (size_t)n * 256 * 768, qkvb, nullptr, nullptr, 8192, 768, 256);
    // 2) attention -> attno           [8192,256]
    attn_kernel<<<256, 256, 0, stream>>>(qkvb, mask, attno);
    // 3) xc = (attno @ Wo[n] + xc) * 0.5
    gemm_f32_kernel<2><<<dim3(64, 4), 256, 0, stream>>>(
        attno, Wo + (size_t)n * 256 * 256, xc, nullptr, xc, 8192, 256, 256);
    // 4) ff = gelu(xc @ W1[n] + b1[n])  [8192,512]
    gemm_f32_kernel<1><<<dim3(64, 8), 256, 0, stream>>>(
        xc, W1 + (size_t)n * 256 * 512, ffb, b1 + (size_t)n * 512, nullptr, 8192, 512, 256);
    // 5) xc = (ff @ W2[n] + b2[n] + xc) * 0.5   (last layer -> d_out)
    gemm_f32_kernel<2><<<dim3(64, 4), 256, 0, stream>>>(
        ffb, W2 + (size_t)n * 512 * 256, (n == 3) ? outp : xc,
        b2 + (size_t)n * 256, xc, 8192, 256, 512);
  }
}

// Round 2
// 2188.118 us; speedup vs baseline: 1.6414x; 1.6414x over previous
//
#include <hip/hip_runtime.h>
#include <hip/hip_bf16.h>
#include <math.h>

#define NEGF (-3.402823466e38f)

// ---------------- prep: pack Wq/Wk/Wv [N,H,D,DK] -> WT [N][D][768] ----------------
// col = ty*256 + h*32 + e   (ty: 0=q 1=k 2=v)
__global__ void prep_wqkv_kernel(const float* __restrict__ Wq,
                                 const float* __restrict__ Wk,
                                 const float* __restrict__ Wv,
                                 float* __restrict__ WT) {
  int idx = blockIdx.x * 256 + threadIdx.x;
  const int total = 4 * 256 * 768;
  if (idx >= total) return;
  int col = idx % 768;
  int d   = (idx / 768) % 256;
  int n   = idx / (768 * 256);
  int ty  = col >> 8;
  int h   = (col >> 5) & 7;
  int e   = col & 31;
  const float* W = (ty == 0) ? Wq : (ty == 1) ? Wk : Wv;
  WT[idx] = W[(((size_t)n * 8 + h) * 256 + d) * 32 + e];
}

// ---------------- generic f32 GEMM, 128x64 tile, BK=32, 256 threads ----------------
// EP: 0 = none, 1 = gelu(acc + bias), 2 = (acc [+ bias] + res) * 0.5
template <int EP>
__global__ __launch_bounds__(256)
void gemm_f32_kernel(const float* __restrict__ A, const float* __restrict__ B,
                     float* __restrict__ C, const float* __restrict__ bias,
                     const float* __restrict__ res, int M, int N, int K) {
  __shared__ float As[128][36];   // pitch 36: 16B-aligned rows, conflict-free frag reads
  __shared__ float Bs[32][64];
  const int t  = threadIdx.x;
  const int r0 = blockIdx.x * 128;
  const int n0 = blockIdx.y * 64;
  const int tc = t & 15;   // 16 col-groups * 4 cols
  const int tr = t >> 4;   // 16 row-groups; rows tr + 16*j

  float acc[8][4];
  #pragma unroll
  for (int j = 0; j < 8; ++j)
    #pragma unroll
    for (int c = 0; c < 4; ++c) acc[j][c] = 0.f;

  for (int k0 = 0; k0 < K; k0 += 32) {
    __syncthreads();
    // stage A tile [128 rows][32 k] : 1024 float4, 4 per thread
    #pragma unroll
    for (int i = 0; i < 4; ++i) {
      int e = t + 256 * i;
      int row = e >> 3, kq = e & 7;
      float4 f = *(const float4*)(A + (size_t)(r0 + row) * K + k0 + kq * 4);
      *(float4*)&As[row][kq * 4] = f;
    }
    // stage B tile [32 k][64 cols] : 512 float4, 2 per thread
    #pragma unroll
    for (int i = 0; i < 2; ++i) {
      int e = t + 256 * i;
      int row = e >> 4, cq = e & 15;
      float4 f = *(const float4*)(B + (size_t)(k0 + row) * N + n0 + cq * 4);
      *(float4*)&Bs[row][cq * 4] = f;
    }
    __syncthreads();
    #pragma unroll
    for (int kk = 0; kk < 32; ++kk) {
      float bfrag[4];
      *(float4*)bfrag = *(const float4*)&Bs[kk][tc * 4];
      float afrag[8];
      #pragma unroll
      for (int j = 0; j < 8; ++j) afrag[j] = As[tr + 16 * j][kk];
      #pragma unroll
      for (int j = 0; j < 8; ++j)
        #pragma unroll
        for (int c = 0; c < 4; ++c) acc[j][c] += afrag[j] * bfrag[c];
    }
  }

  #pragma unroll
  for (int j = 0; j < 8; ++j) {
    int row = r0 + tr + 16 * j;
    size_t off = (size_t)row * N + n0 + tc * 4;
    float4 v;
    float* pv = (float*)&v;
    #pragma unroll
    for (int c = 0; c < 4; ++c) {
      float x = acc[j][c];
      if (EP == 1) {
        x += bias[n0 + tc * 4 + c];
        x = 0.5f * x * (1.f + erff(x * 0.70710678118654752f));
      } else if (EP == 2) {
        if (bias) x += bias[n0 + tc * 4 + c];
        x = (x + res[off + c]) * 0.5f;
      }
      pv[c] = x;
    }
    *(float4*)(C + off) = v;
  }
}

// ---------------- fused flash attention, split-KV across 4 waves ----------------
// qkv layout: [B*L][768], q at col 0 + h*32, k at 256 + h*32, v at 512 + h*32
// out: [B*L][256] with col = h*32 + e
// grid: b*256 + h*32 + qblk  (1024 WGs); 256 thr = 4 waves; 64 queries/WG (1/lane);
// wave w covers keys [w*512, w*512+512) in 16 chunks of 32, wave-private LDS slab.
__global__ __launch_bounds__(256, 4)
void attn_kernel(const float* __restrict__ qkv, const float* __restrict__ mask,
                 float* __restrict__ out) {
  __shared__ float slab[4][2][32][36];   // [wave][K/V][key][dim(+pad)]; 36 KiB
  __shared__ float msk[4][32];
  const int t    = threadIdx.x;
  const int lane = t & 63;
  const int wave = t >> 6;
  const int wg   = blockIdx.x;
  const int qblk = wg & 31;
  const int h    = (wg >> 5) & 7;
  const int b    = wg >> 8;
  const int bL   = b * 2048;
  const int qrow = qblk * 64 + lane;

  // load q into registers
  const float* qp = qkv + ((size_t)(bL + qrow)) * 768 + h * 32;
  float qv[32];
  #pragma unroll
  for (int i = 0; i < 8; ++i) {
    float4 f = *(const float4*)(qp + 4 * i);
    qv[4*i] = f.x; qv[4*i+1] = f.y; qv[4*i+2] = f.z; qv[4*i+3] = f.w;
  }
  const float mq = mask[bL + qrow];

  float m = -INFINITY, l = 0.f;
  float o[32];
  #pragma unroll
  for (int i = 0; i < 32; ++i) o[i] = 0.f;

  const int kbase = wave * 512;
  const int srow  = (lane + 0) >> 3;   // staging row/col per lane (i folded below)
  float4 kr0, kr1, kr2, kr3, vr0, vr1, vr2, vr3;
  float  mr;

  #define LOADC(k0)                                                            \
    {                                                                          \
      _Pragma("unroll")                                                        \
      for (int i = 0; i < 4; ++i) {                                            \
        int e = lane + 64 * i;                                                 \
        int row = e >> 3, c4 = (e & 7) * 4;                                    \
        size_t base = ((size_t)(bL + (k0) + row)) * 768 + 256 + h * 32 + c4;   \
        float4 kf = *(const float4*)(qkv + base);                              \
        float4 vf = *(const float4*)(qkv + base + 256);                        \
        if (i == 0) { kr0 = kf; vr0 = vf; }                                    \
        else if (i == 1) { kr1 = kf; vr1 = vf; }                               \
        else if (i == 2) { kr2 = kf; vr2 = vf; }                               \
        else { kr3 = kf; vr3 = vf; }                                           \
      }                                                                        \
      mr = (lane < 32) ? mask[bL + (k0) + lane] : 0.f;                         \
    }

  LOADC(kbase);
  for (int c = 0; c < 16; ++c) {
    // commit staged regs to this wave's private slab (no cross-wave sync needed)
    #pragma unroll
    for (int i = 0; i < 4; ++i) {
      int e = lane + 64 * i;
      int row = e >> 3, c4 = (e & 7) * 4;
      float4 kf = (i == 0) ? kr0 : (i == 1) ? kr1 : (i == 2) ? kr2 : kr3;
      float4 vf = (i == 0) ? vr0 : (i == 1) ? vr1 : (i == 2) ? vr2 : vr3;
      *(float4*)&slab[wave][0][row][c4] = kf;
      *(float4*)&slab[wave][1][row][c4] = vf;
    }
    if (lane < 32) msk[wave][lane] = mr;
    if (c + 1 < 16) LOADC(kbase + (c + 1) * 32);   // prefetch overlaps compute

    #pragma unroll 2
    for (int j = 0; j < 32; ++j) {
      const float4* kj = (const float4*)&slab[wave][0][j][0];
      float s0 = 0.f, s1 = 0.f, s2 = 0.f, s3 = 0.f;
      #pragma unroll
      for (int i = 0; i < 8; ++i) {
        float4 kf = kj[i];
        s0 += qv[4*i+0] * kf.x;
        s1 += qv[4*i+1] * kf.y;
        s2 += qv[4*i+2] * kf.z;
        s3 += qv[4*i+3] * kf.w;
      }
      float s   = (s0 + s1) + (s2 + s3);
      float smk = (mq * msk[wave][j] != 0.f) ? s : NEGF;  // replica of +finfo.min
      if (__any(smk > m + 8.f)) {          // wave-uniform, rare: deferred rescale
        float mn = fmaxf(m, smk);
        float r  = __expf(m - mn);         // m=-inf first time -> r=0
        l *= r;
        #pragma unroll
        for (int i = 0; i < 32; ++i) o[i] *= r;
        m = mn;
      }
      float p = __expf(smk - m);           // bounded by e^8
      l += p;
      const float* vj = &slab[wave][1][j][0];
      #pragma unroll
      for (int i = 0; i < 32; ++i) o[i] += p * vj[i];
    }
  }
  #undef LOADC

  // ---- merge 4 per-wave partials via LDS (slabs are dead now) ----
  __syncthreads();
  float* comb = &slab[0][0][0][0];         // alias: [4][64][36] = same 36 KiB
  float* cp = comb + (wave * 64 + lane) * 36;
  #pragma unroll
  for (int i = 0; i < 32; ++i) cp[i] = o[i];
  cp[32] = m; cp[33] = l;
  __syncthreads();

  {
    int q  = t >> 2;                        // 0..63
    int cc = t & 3;                         // 8-dim chunk
    float mw[4], lw[4];
    #pragma unroll
    for (int w = 0; w < 4; ++w) {
      mw[w] = comb[(w * 64 + q) * 36 + 32];
      lw[w] = comb[(w * 64 + q) * 36 + 33];
    }
    float M = fmaxf(fmaxf(mw[0], mw[1]), fmaxf(mw[2], mw[3]));
    float rw[4], L = 0.f;
    #pragma unroll
    for (int w = 0; w < 4; ++w) { rw[w] = __expf(mw[w] - M); L += rw[w] * lw[w]; }
    float inv = 1.f / L;
    float res[8];
    #pragma unroll
    for (int d = 0; d < 8; ++d) {
      float acc = 0.f;
      #pragma unroll
      for (int w = 0; w < 4; ++w) acc += rw[w] * comb[(w * 64 + q) * 36 + cc * 8 + d];
      res[d] = acc * inv;
    }
    float* op = out + ((size_t)(bL + qblk * 64 + q)) * 256 + h * 32 + cc * 8;
    *(float4*)op       = make_float4(res[0], res[1], res[2], res[3]);
    *(float4*)(op + 4) = make_float4(res[4], res[5], res[6], res[7]);
  }
}

// ---------------- launch ----------------
extern "C" void kernel_launch(void* const* d_in, const int* in_sizes, int n_in,
                              void* d_out, int out_size, void* d_ws, size_t ws_size,
                              hipStream_t stream) {
  const float* x    = (const float*)d_in[0];
  const float* mask = (const float*)d_in[1];
  const float* Wq   = (const float*)d_in[2];
  const float* Wk   = (const float*)d_in[3];
  const float* Wv   = (const float*)d_in[4];
  const float* Wo   = (const float*)d_in[5];
  const float* W1   = (const float*)d_in[6];
  const float* b1   = (const float*)d_in[7];
  const float* W2   = (const float*)d_in[8];
  const float* b2   = (const float*)d_in[9];
  float* outp = (float*)d_out;

  char* ws = (char*)d_ws;
  float* xc     = (float*)(ws);                               // 8 MiB  [8192][256]
  float* qkvb   = (float*)(ws + ((size_t)8  << 20));          // 24 MiB [8192][768]
  float* ffb    = qkvb;                                       // reuse (disjoint in time)
  float* attno  = (float*)(ws + ((size_t)32 << 20));          // 8 MiB  [8192][256]
  float* wqkvT  = (float*)(ws + ((size_t)40 << 20));          // 3 MiB  [4][256][768]

  // xc = x
  hipMemcpyAsync(xc, x, (size_t)8192 * 256 * sizeof(float),
                 hipMemcpyDeviceToDevice, stream);
  // pack qkv weights
  prep_wqkv_kernel<<<3072, 256, 0, stream>>>(Wq, Wk, Wv, wqkvT);

  for (int n = 0; n < 4; ++n) {
    // 1) qkv = xc @ WqkvT[n]          [8192,768]
    gemm_f32_kernel<0><<<dim3(64, 12), 256, 0, stream>>>(
        xc, wqkvT + (size_t)n * 256 * 768, qkvb, nullptr, nullptr, 8192, 768, 256);
    // 2) attention -> attno           [8192,256]
    attn_kernel<<<1024, 256, 0, stream>>>(qkvb, mask, attno);
    // 3) xc = (attno @ Wo[n] + xc) * 0.5
    gemm_f32_kernel<2><<<dim3(64, 4), 256, 0, stream>>>(
        attno, Wo + (size_t)n * 256 * 256, xc, nullptr, xc, 8192, 256, 256);
    // 4) ff = gelu(xc @ W1[n] + b1[n])  [8192,512]
    gemm_f32_kernel<1><<<dim3(64, 8), 256, 0, stream>>>(
        xc, W1 + (size_t)n * 256 * 512, ffb, b1 + (size_t)n * 512, nullptr, 8192, 512, 256);
    // 5) xc = (ff @ W2[n] + b2[n] + xc) * 0.5   (last layer -> d_out)
    gemm_f32_kernel<2><<<dim3(64, 4), 256, 0, stream>>>(
        ffb, W2 + (size_t)n * 512 * 256, (n == 3) ? outp : xc,
        b2 + (size_t)n * 256, xc, 8192, 256, 512);
  }
}

// Round 3
// 1715.840 us; speedup vs baseline: 2.0932x; 1.2752x over previous
//
#include <hip/hip_runtime.h>
#include <hip/hip_bf16.h>
#include <math.h>

#define NEGF (-3.402823466e38f)
#define AS1 __attribute__((address_space(1)))
#define AS3 __attribute__((address_space(3)))

__device__ __forceinline__ float dpp_xor1(float x) {
  int v = __builtin_amdgcn_update_dpp(0, __builtin_bit_cast(int, x),
                                      0xB1, 0xF, 0xF, true);  // quad_perm [1,0,3,2]
  return __builtin_bit_cast(float, v);
}

__device__ __forceinline__ void gll16(const float* g, AS3 float* l) {
  __builtin_amdgcn_global_load_lds((const AS1 void*)g, (AS3 void*)l, 16, 0, 0);
}

// ---------------- prep: pack Wq/Wk/Wv [N,H,D,DK] -> WT [N][D][768] ----------------
__global__ void prep_wqkv_kernel(const float* __restrict__ Wq,
                                 const float* __restrict__ Wk,
                                 const float* __restrict__ Wv,
                                 float* __restrict__ WT) {
  int idx = blockIdx.x * 256 + threadIdx.x;
  const int total = 4 * 256 * 768;
  if (idx >= total) return;
  int col = idx % 768;
  int d   = (idx / 768) % 256;
  int n   = idx / (768 * 256);
  int ty  = col >> 8;
  int h   = (col >> 5) & 7;
  int e   = col & 31;
  const float* W = (ty == 0) ? Wq : (ty == 1) ? Wk : Wv;
  WT[idx] = W[(((size_t)n * 8 + h) * 256 + d) * 32 + e];
}

// ---------------- generic f32 GEMM, 128x64 tile, BK=32, 256 threads ----------------
template <int EP>
__global__ __launch_bounds__(256)
void gemm_f32_kernel(const float* __restrict__ A, const float* __restrict__ B,
                     float* __restrict__ C, const float* __restrict__ bias,
                     const float* __restrict__ res, int M, int N, int K) {
  __shared__ float As[128][36];
  __shared__ float Bs[32][64];
  const int t  = threadIdx.x;
  const int r0 = blockIdx.x * 128;
  const int n0 = blockIdx.y * 64;
  const int tc = t & 15;
  const int tr = t >> 4;

  float acc[8][4];
  #pragma unroll
  for (int j = 0; j < 8; ++j)
    #pragma unroll
    for (int c = 0; c < 4; ++c) acc[j][c] = 0.f;

  for (int k0 = 0; k0 < K; k0 += 32) {
    __syncthreads();
    #pragma unroll
    for (int i = 0; i < 4; ++i) {
      int e = t + 256 * i;
      int row = e >> 3, kq = e & 7;
      float4 f = *(const float4*)(A + (size_t)(r0 + row) * K + k0 + kq * 4);
      *(float4*)&As[row][kq * 4] = f;
    }
    #pragma unroll
    for (int i = 0; i < 2; ++i) {
      int e = t + 256 * i;
      int row = e >> 4, cq = e & 15;
      float4 f = *(const float4*)(B + (size_t)(k0 + row) * N + n0 + cq * 4);
      *(float4*)&Bs[row][cq * 4] = f;
    }
    __syncthreads();
    #pragma unroll
    for (int kk = 0; kk < 32; ++kk) {
      float bfrag[4];
      *(float4*)bfrag = *(const float4*)&Bs[kk][tc * 4];
      float afrag[8];
      #pragma unroll
      for (int j = 0; j < 8; ++j) afrag[j] = As[tr + 16 * j][kk];
      #pragma unroll
      for (int j = 0; j < 8; ++j)
        #pragma unroll
        for (int c = 0; c < 4; ++c) acc[j][c] += afrag[j] * bfrag[c];
    }
  }

  #pragma unroll
  for (int j = 0; j < 8; ++j) {
    int row = r0 + tr + 16 * j;
    size_t off = (size_t)row * N + n0 + tc * 4;
    float4 v;
    float* pv = (float*)&v;
    #pragma unroll
    for (int c = 0; c < 4; ++c) {
      float x = acc[j][c];
      if (EP == 1) {
        x += bias[n0 + tc * 4 + c];
        x = 0.5f * x * (1.f + erff(x * 0.70710678118654752f));
      } else if (EP == 2) {
        if (bias) x += bias[n0 + tc * 4 + c];
        x = (x + res[off + c]) * 0.5f;
      }
      pv[c] = x;
    }
    *(float4*)(C + off) = v;
  }
}

// ---------------- fused flash attention, team-tiled, DMA-staged ----------------
// qkv: [B*L][768] (q @0, k @256, v @512, +h*32). out: [B*L][256].
// grid 512 = b*128 + h*16 + qblk. WG = 4 waves; all waves cover the same 128
// queries (team = lane>>1 owns 4 queries, half = lane&1 owns 16 dims);
// wave w handles keys [w*512, w*512+512) in 16 chunks of 32 (dbuf DMA slabs).
__global__ __launch_bounds__(256, 2)
void attn_kernel(const float* __restrict__ qkv, const float* __restrict__ mask,
                 float* __restrict__ out) {
  __shared__ float sl[18432];       // 72 KiB: [0,16384) K/V slabs, [16384,18432) mask
  const int t    = threadIdx.x;
  const int lane = t & 63, wave = t >> 6;
  const int wg   = blockIdx.x;
  const int qblk = wg & 15;
  const int h    = (wg >> 4) & 7;
  const int b    = wg >> 7;
  const int bL   = b * 2048;

  // stage whole mask row for this batch (2048 f32 = 8 KiB)
  {
    float4* mf = (float4*)(sl + 16384);
    const float4* mp = (const float4*)(mask + bL);
    mf[t]       = mp[t];
    mf[t + 256] = mp[t + 256];
  }

  const int team = lane >> 1, half = lane & 1;
  float q[4][16], o[4][16], m[4], l[4], mq[4];
  #pragma unroll
  for (int i = 0; i < 4; ++i) {
    int qi = qblk * 128 + i * 32 + team;
    const float* qp = qkv + (size_t)(bL + qi) * 768 + h * 32 + half * 16;
    #pragma unroll
    for (int c = 0; c < 4; ++c) {
      float4 f = *(const float4*)(qp + 4 * c);
      q[i][4*c] = f.x; q[i][4*c+1] = f.y; q[i][4*c+2] = f.z; q[i][4*c+3] = f.w;
    }
    mq[i] = mask[bL + qi];
    m[i] = -INFINITY; l[i] = 0.f;
    #pragma unroll
    for (int d = 0; d < 16; ++d) o[i][d] = 0.f;
  }
  __syncthreads();   // mask slab ready

  // DMA slabs: per wave [buf][K/V][32 rows][32 dims], 4096 floats
  AS3 float* slab = (AS3 float*)sl + wave * 4096;
  const int lrow = lane >> 3, lcol = (lane & 7) * 4;
  const float* gbase = qkv + (size_t)(bL + wave * 512 + lrow) * 768 + 256 + h * 32 + lcol;

  #define ISSUE(c, buf)                                                        \
    {                                                                          \
      const float* g = gbase + (size_t)(c) * 32 * 768;                         \
      AS3 float* dK = slab + (buf) * 2048;                                     \
      _Pragma("unroll")                                                        \
      for (int i = 0; i < 4; ++i) {                                            \
        gll16(g + i * 8 * 768,       dK + i * 256);                            \
        gll16(g + i * 8 * 768 + 256, dK + 1024 + i * 256);                     \
      }                                                                        \
    }

  ISSUE(0, 0);
  const float* mwave = sl + 16384 + wave * 512;

  #pragma unroll 1
  for (int c = 0; c < 16; ++c) {
    const int buf = c & 1;
    if (c < 15) {
      ISSUE(c + 1, buf ^ 1);
      asm volatile("s_waitcnt vmcnt(8)" ::: "memory");   // drain chunk c's 8 DMAs
    } else {
      asm volatile("s_waitcnt vmcnt(0)" ::: "memory");
    }
    const float* Kb = (const float*)(sl + wave * 4096 + buf * 2048);
    const float* Vb = Kb + 1024;
    const float* mr = mwave + c * 32;

    #pragma unroll 2
    for (int j = 0; j < 32; ++j) {
      float kk[16];
      {
        const float4* kp = (const float4*)(Kb + j * 32 + half * 16);
        *(float4*)&kk[0]  = kp[0]; *(float4*)&kk[4]  = kp[1];
        *(float4*)&kk[8]  = kp[2]; *(float4*)&kk[12] = kp[3];
      }
      float sv[4] = {0.f, 0.f, 0.f, 0.f};
      #pragma unroll
      for (int d = 0; d < 16; ++d) {
        sv[0] += q[0][d] * kk[d]; sv[1] += q[1][d] * kk[d];
        sv[2] += q[2][d] * kk[d]; sv[3] += q[3][d] * kk[d];
      }
      #pragma unroll
      for (int i = 0; i < 4; ++i) sv[i] += dpp_xor1(sv[i]);   // team reduce (VALU)
      const float mk = mr[j];
      #pragma unroll
      for (int i = 0; i < 4; ++i) sv[i] = (mq[i] * mk != 0.f) ? sv[i] : NEGF;

      float dmax = fmaxf(fmaxf(sv[0] - m[0], sv[1] - m[1]),
                         fmaxf(sv[2] - m[2], sv[3] - m[3]));
      if (__any(dmax > 8.f)) {           // rare deferred rescale (wave-uniform)
        #pragma unroll
        for (int i = 0; i < 4; ++i) {
          float mn = fmaxf(m[i], sv[i]);
          float r  = __expf(m[i] - mn);  // m=-inf first time -> r=0
          l[i] *= r;
          #pragma unroll
          for (int d = 0; d < 16; ++d) o[i][d] *= r;
          m[i] = mn;
        }
      }
      float vv[16];
      {
        const float4* vp = (const float4*)(Vb + j * 32 + half * 16);
        *(float4*)&vv[0]  = vp[0]; *(float4*)&vv[4]  = vp[1];
        *(float4*)&vv[8]  = vp[2]; *(float4*)&vv[12] = vp[3];
      }
      #pragma unroll
      for (int i = 0; i < 4; ++i) {
        float p = __expf(sv[i] - m[i]);  // bounded by e^8; NEGF rows -> p=1 uniform
        l[i] += p;
        #pragma unroll
        for (int d = 0; d < 16; ++d) o[i][d] += p * vv[d];
      }
    }
  }
  #undef ISSUE

  // ---- merge per-wave partials: comb[w*128 + r][34] over slab space ----
  __syncthreads();
  #pragma unroll
  for (int i = 0; i < 4; ++i) {
    float* cb = sl + (size_t)(wave * 128 + i * 32 + team) * 34;
    #pragma unroll
    for (int d = 0; d < 16; ++d) cb[half * 16 + d] = o[i][d];
    if (half == 0) { cb[32] = m[i]; cb[33] = l[i]; }
  }
  __syncthreads();

  {
    const int qq = t >> 1, hh = t & 1;
    float mw[4], lw[4];
    #pragma unroll
    for (int w = 0; w < 4; ++w) {
      mw[w] = sl[(size_t)(w * 128 + qq) * 34 + 32];
      lw[w] = sl[(size_t)(w * 128 + qq) * 34 + 33];
    }
    float M = fmaxf(fmaxf(mw[0], mw[1]), fmaxf(mw[2], mw[3]));
    float rw[4], L = 0.f;
    #pragma unroll
    for (int w = 0; w < 4; ++w) { rw[w] = __expf(mw[w] - M); L += rw[w] * lw[w]; }
    const float inv = 1.f / L;
    float acc[16];
    #pragma unroll
    for (int d = 0; d < 16; ++d) acc[d] = 0.f;
    #pragma unroll
    for (int w = 0; w < 4; ++w) {
      const float* cb = sl + (size_t)(w * 128 + qq) * 34 + hh * 16;
      #pragma unroll
      for (int d = 0; d < 16; ++d) acc[d] += rw[w] * cb[d];
    }
    float* op = out + (size_t)(bL + qblk * 128 + qq) * 256 + h * 32 + hh * 16;
    #pragma unroll
    for (int c4 = 0; c4 < 4; ++c4)
      *(float4*)(op + 4 * c4) = make_float4(acc[4*c4] * inv, acc[4*c4+1] * inv,
                                            acc[4*c4+2] * inv, acc[4*c4+3] * inv);
  }
}

// ---------------- launch ----------------
extern "C" void kernel_launch(void* const* d_in, const int* in_sizes, int n_in,
                              void* d_out, int out_size, void* d_ws, size_t ws_size,
                              hipStream_t stream) {
  const float* x    = (const float*)d_in[0];
  const float* mask = (const float*)d_in[1];
  const float* Wq   = (const float*)d_in[2];
  const float* Wk   = (const float*)d_in[3];
  const float* Wv   = (const float*)d_in[4];
  const float* Wo   = (const float*)d_in[5];
  const float* W1   = (const float*)d_in[6];
  const float* b1   = (const float*)d_in[7];
  const float* W2   = (const float*)d_in[8];
  const float* b2   = (const float*)d_in[9];
  float* outp = (float*)d_out;

  char* ws = (char*)d_ws;
  float* xc     = (float*)(ws);                               // 8 MiB  [8192][256]
  float* qkvb   = (float*)(ws + ((size_t)8  << 20));          // 24 MiB [8192][768]
  float* ffb    = qkvb;                                       // reuse (disjoint in time)
  float* attno  = (float*)(ws + ((size_t)32 << 20));          // 8 MiB  [8192][256]
  float* wqkvT  = (float*)(ws + ((size_t)40 << 20));          // 3 MiB  [4][256][768]

  hipMemcpyAsync(xc, x, (size_t)8192 * 256 * sizeof(float),
                 hipMemcpyDeviceToDevice, stream);
  prep_wqkv_kernel<<<3072, 256, 0, stream>>>(Wq, Wk, Wv, wqkvT);

  for (int n = 0; n < 4; ++n) {
    gemm_f32_kernel<0><<<dim3(64, 12), 256, 0, stream>>>(
        xc, wqkvT + (size_t)n * 256 * 768, qkvb, nullptr, nullptr, 8192, 768, 256);
    attn_kernel<<<512, 256, 0, stream>>>(qkvb, mask, attno);
    gemm_f32_kernel<2><<<dim3(64, 4), 256, 0, stream>>>(
        attno, Wo + (size_t)n * 256 * 256, xc, nullptr, xc, 8192, 256, 256);
    gemm_f32_kernel<1><<<dim3(64, 8), 256, 0, stream>>>(
        xc, W1 + (size_t)n * 256 * 512, ffb, b1 + (size_t)n * 512, nullptr, 8192, 512, 256);
    gemm_f32_kernel<2><<<dim3(64, 4), 256, 0, stream>>>(
        ffb, W2 + (size_t)n * 512 * 256, (n == 3) ? outp : xc,
        b2 + (size_t)n * 256, xc, 8192, 256, 512);
  }
}

// Round 6
// 1596.211 us; speedup vs baseline: 2.2501x; 1.0749x over previous
//
#include <hip/hip_runtime.h>
#include <hip/hip_bf16.h>
#include <math.h>

#define NEGF (-3.402823466e38f)

typedef unsigned int u32;
typedef unsigned short u16;
typedef __attribute__((ext_vector_type(8))) short s16x8;
typedef __attribute__((ext_vector_type(4))) float f32x4;

#define MFMA16(a, b, c) __builtin_amdgcn_mfma_f32_16x16x32_bf16(a, b, c, 0, 0, 0)

// pack (low16=trunc-bf16(a), high16=trunc-bf16(b)) into one u32
__device__ __forceinline__ u32 pkhi(float a, float b) {
  return __builtin_amdgcn_perm(__builtin_bit_cast(u32, b),
                               __builtin_bit_cast(u32, a), 0x07060302u);
}
__device__ __forceinline__ float bftrunc(float x) {
  return __builtin_bit_cast(float, __builtin_bit_cast(u32, x) & 0xFFFF0000u);
}

// ---------------- prep: pack Wq/Wk/Wv [N,H,D,DK] -> WT [N][D][768] ----------------
__global__ void prep_wqkv_kernel(const float* __restrict__ Wq,
                                 const float* __restrict__ Wk,
                                 const float* __restrict__ Wv,
                                 float* __restrict__ WT) {
  int idx = blockIdx.x * 256 + threadIdx.x;
  const int total = 4 * 256 * 768;
  if (idx >= total) return;
  int col = idx % 768;
  int d   = (idx / 768) % 256;
  int n   = idx / (768 * 256);
  int ty  = col >> 8;
  int h   = (col >> 5) & 7;
  int e   = col & 31;
  const float* W = (ty == 0) ? Wq : (ty == 1) ? Wk : Wv;
  WT[idx] = W[(((size_t)n * 8 + h) * 256 + d) * 32 + e];
}

// ---------------- generic f32 GEMM, 128x64 tile, BK=32, 256 threads ----------------
// EP: 0 none | 1 gelu(acc+bias) | 2 (acc[+bias]+res)*0.5 | 3 split-bf16 hi/lo out
template <int EP>
__global__ __launch_bounds__(256)
void gemm_f32_kernel(const float* __restrict__ A, const float* __restrict__ B,
                     float* __restrict__ C, const float* __restrict__ bias,
                     const float* __restrict__ res, u16* __restrict__ Ch,
                     u16* __restrict__ Cl, int M, int N, int K) {
  __shared__ float As[128][36];
  __shared__ float Bs[32][64];
  const int t  = threadIdx.x;
  const int r0 = blockIdx.x * 128;
  const int n0 = blockIdx.y * 64;
  const int tc = t & 15;
  const int tr = t >> 4;

  float acc[8][4];
  #pragma unroll
  for (int j = 0; j < 8; ++j)
    #pragma unroll
    for (int c = 0; c < 4; ++c) acc[j][c] = 0.f;

  for (int k0 = 0; k0 < K; k0 += 32) {
    __syncthreads();
    #pragma unroll
    for (int i = 0; i < 4; ++i) {
      int e = t + 256 * i;
      int row = e >> 3, kq = e & 7;
      float4 f = *(const float4*)(A + (size_t)(r0 + row) * K + k0 + kq * 4);
      *(float4*)&As[row][kq * 4] = f;
    }
    #pragma unroll
    for (int i = 0; i < 2; ++i) {
      int e = t + 256 * i;
      int row = e >> 4, cq = e & 15;
      float4 f = *(const float4*)(B + (size_t)(k0 + row) * N + n0 + cq * 4);
      *(float4*)&Bs[row][cq * 4] = f;
    }
    __syncthreads();
    #pragma unroll
    for (int kk = 0; kk < 32; ++kk) {
      float bfrag[4];
      *(float4*)bfrag = *(const float4*)&Bs[kk][tc * 4];
      float afrag[8];
      #pragma unroll
      for (int j = 0; j < 8; ++j) afrag[j] = As[tr + 16 * j][kk];
      #pragma unroll
      for (int j = 0; j < 8; ++j)
        #pragma unroll
        for (int c = 0; c < 4; ++c) acc[j][c] += afrag[j] * bfrag[c];
    }
  }

  #pragma unroll
  for (int j = 0; j < 8; ++j) {
    int row = r0 + tr + 16 * j;
    size_t off = (size_t)row * N + n0 + tc * 4;
    float xa[4];
    #pragma unroll
    for (int c = 0; c < 4; ++c) {
      float x = acc[j][c];
      if (EP == 1) {
        x += bias[n0 + tc * 4 + c];
        x = 0.5f * x * (1.f + erff(x * 0.70710678118654752f));
      } else if (EP == 2) {
        if (bias) x += bias[n0 + tc * 4 + c];
        x = (x + res[off + c]) * 0.5f;
      }
      xa[c] = x;
    }
    if (EP == 3) {
      u32 h01 = pkhi(xa[0], xa[1]), h23 = pkhi(xa[2], xa[3]);
      u32 l01 = pkhi(xa[0] - bftrunc(xa[0]), xa[1] - bftrunc(xa[1]));
      u32 l23 = pkhi(xa[2] - bftrunc(xa[2]), xa[3] - bftrunc(xa[3]));
      *(uint2*)(Ch + off) = make_uint2(h01, h23);
      *(uint2*)(Cl + off) = make_uint2(l01, l23);
    } else {
      *(float4*)(C + off) = make_float4(xa[0], xa[1], xa[2], xa[3]);
    }
  }
}

// ---------------- V transpose: qh/ql [8192][768] -> vt [b][h][32][2048] bf16 ------
__global__ __launch_bounds__(256)
void vtrans_kernel(const u16* __restrict__ qh, const u16* __restrict__ ql,
                   u16* __restrict__ vth, u16* __restrict__ vtl) {
  __shared__ u16 T[128][36];
  const int wg = blockIdx.x;
  const int tb = wg & 15, h = (wg >> 4) & 7, b = wg >> 7;
  const int t = threadIdx.x;
  const int tok = t >> 1, eo = (t & 1) * 16;
  const int e = t >> 3, seg = t & 7;
  #pragma unroll 1
  for (int pass = 0; pass < 2; ++pass) {
    const u16* src = pass ? ql : qh;
    u16* dst = pass ? vtl : vth;
    if (pass) __syncthreads();
    const u16* p = src + (size_t)(b * 2048 + tb * 128 + tok) * 768 + 512 + h * 32 + eo;
    uint2 u0 = *(const uint2*)p;
    uint2 u1 = *(const uint2*)(p + 4);
    uint2 u2 = *(const uint2*)(p + 8);
    uint2 u3 = *(const uint2*)(p + 12);
    *(uint2*)&T[tok][eo]      = u0;
    *(uint2*)&T[tok][eo + 4]  = u1;
    *(uint2*)&T[tok][eo + 8]  = u2;
    *(uint2*)&T[tok][eo + 12] = u3;
    __syncthreads();
    u32 w[8];
    #pragma unroll
    for (int i = 0; i < 8; ++i) {
      u32 lo16 = T[seg * 16 + 2 * i][e];
      u32 hi16 = T[seg * 16 + 2 * i + 1][e];
      w[i] = lo16 | (hi16 << 16);
    }
    u16* q = dst + ((size_t)((b * 8 + h) * 32 + e)) * 2048 + tb * 128 + seg * 16;
    *(uint4*)q       = make_uint4(w[0], w[1], w[2], w[3]);
    *(uint4*)(q + 8) = make_uint4(w[4], w[5], w[6], w[7]);
  }
}

// ---------------- MFMA flash attention, 16x16x32 (HW-verified layouts) -------------
// 1 wave = 16 queries over all 2048 keys. grid 4096 = qt*32 + bh; 64 threads.
// C/D map (m89-verified): col=lane&15, row=(lane>>4)*4+reg.
// A/B frags: contiguous 8 k-elems per lane at k=(lane>>4)*8 (m97-consistent).
// Cross-lane: __shfl_xor only. P redistribution via wave-private LDS (round-2 idiom).
// exp args clamped, divisor guarded: NaN structurally impossible.
__global__ __launch_bounds__(64)
void attn_mfma_kernel(const u16* __restrict__ qh, const u16* __restrict__ ql,
                      const u16* __restrict__ vth, const u16* __restrict__ vtl,
                      const float* __restrict__ mask, float* __restrict__ out) {
  __shared__ u16 PH[16][40];   // P hi, row pitch 40 u16 (80 B, 16B-aligned)
  __shared__ u16 PL[16][40];   // P lo
  const int wg = blockIdx.x;
  const int bh = wg & 31, qt = wg >> 5;        // qt in [0,128)
  const int b = bh >> 3, h = bh & 7;
  const int bL = b * 2048;
  const int lane = threadIdx.x;
  const int q = lane & 15, g = lane >> 4;      // g in [0,4)

  // Q as B-operand: query=lane&15, dims g*8..g*8+7 (contiguous 8)
  const size_t qoff = (size_t)(bL + qt * 16 + q) * 768 + h * 32 + g * 8;
  const s16x8 Qh  = *(const s16x8*)(qh + qoff);
  const s16x8 Qlo = *(const s16x8*)(ql + qoff);
  const float mq = mask[bL + qt * 16 + q];

  // K as A-operand: key = khalf*16 + (lane&15), dims g*8..+7
  const u16* kb_h = qh + (size_t)(bL + q) * 768 + 256 + h * 32 + g * 8;
  const u16* kb_l = ql + (size_t)(bL + q) * 768 + 256 + h * 32 + g * 8;
  // V^T as A-operand: dim = chunk*16 + (lane&15), keys t*32 + g*8..+7
  const u16* vb_h0 = vth + ((size_t)(bh * 32 + q)) * 2048 + g * 8;
  const u16* vb_h1 = vth + ((size_t)(bh * 32 + 16 + q)) * 2048 + g * 8;
  const u16* vb_l0 = vtl + ((size_t)(bh * 32 + q)) * 2048 + g * 8;
  const u16* vb_l1 = vtl + ((size_t)(bh * 32 + 16 + q)) * 2048 + g * 8;
  const float* mb = mask + bL + (lane & 31);

  f32x4 Oa = {}, Ob = {};
  float m = NEGF, l = 0.f;

  #pragma unroll 1
  for (int t = 0; t < 64; ++t) {
    const size_t ko = (size_t)t * 32 * 768;
    const s16x8 K0h = *(const s16x8*)(kb_h + ko);
    const s16x8 K1h = *(const s16x8*)(kb_h + ko + 16 * 768);
    const s16x8 K0l = *(const s16x8*)(kb_l + ko);
    const s16x8 K1l = *(const s16x8*)(kb_l + ko + 16 * 768);
    const s16x8 V0h = *(const s16x8*)(vb_h0 + t * 32);
    const s16x8 V1h = *(const s16x8*)(vb_h1 + t * 32);
    const s16x8 V0l = *(const s16x8*)(vb_l0 + t * 32);
    const s16x8 V1l = *(const s16x8*)(vb_l1 + t * 32);
    const float mk = mb[t * 32];

    // S^T tiles: D[key][query], one MFMA covers full DK=32
    f32x4 S0 = {}, S1 = {};
    S0 = MFMA16(K0h, Qh,  S0);  S1 = MFMA16(K1h, Qh,  S1);
    S0 = MFMA16(K0l, Qh,  S0);  S1 = MFMA16(K1l, Qh,  S1);
    S0 = MFMA16(K0h, Qlo, S0);  S1 = MFMA16(K1h, Qlo, S1);

    u32 em = (u32)__ballot(mk != 0.f);   // bit j = key j of this 32-key tile
    em = (mq != 0.f) ? em : 0u;
    float se[8];
    #pragma unroll
    for (int r = 0; r < 4; ++r) {
      se[r]     = ((em >> (g * 4 + r)) & 1u)      ? S0[r] : NEGF;
      se[4 + r] = ((em >> (16 + g * 4 + r)) & 1u) ? S1[r] : NEGF;
    }
    // row max: local 8, then across the 4 g-groups (lane^16, lane^32)
    float mt = fmaxf(fmaxf(fmaxf(se[0], se[1]), fmaxf(se[2], se[3])),
                     fmaxf(fmaxf(se[4], se[5]), fmaxf(se[6], se[7])));
    mt = fmaxf(mt, __shfl_xor(mt, 16));
    mt = fmaxf(mt, __shfl_xor(mt, 32));
    const float mn = fmaxf(m, mt);
    const float rr = __expf(m - mn);     // m <= mn by construction
    l *= rr;
    #pragma unroll
    for (int r = 0; r < 4; ++r) { Oa[r] *= rr; Ob[r] *= rr; }
    m = mn;
    float p[8];
    #pragma unroll
    for (int r = 0; r < 8; ++r) p[r] = __expf(fminf(se[r] - m, 60.f));
    l += (((p[0] + p[1]) + (p[2] + p[3])) + ((p[4] + p[5]) + (p[6] + p[7])));

    // P^T redistribute via LDS: lane holds keys {4g..4g+3, 16+4g..+3} of query q;
    // B-frag needs keys g*8..g*8+7 of query q.
    u32 ph0 = pkhi(p[0], p[1]), ph1 = pkhi(p[2], p[3]);
    u32 ph2 = pkhi(p[4], p[5]), ph3 = pkhi(p[6], p[7]);
    u32 pl0 = pkhi(p[0] - bftrunc(p[0]), p[1] - bftrunc(p[1]));
    u32 pl1 = pkhi(p[2] - bftrunc(p[2]), p[3] - bftrunc(p[3]));
    u32 pl2 = pkhi(p[4] - bftrunc(p[4]), p[5] - bftrunc(p[5]));
    u32 pl3 = pkhi(p[6] - bftrunc(p[6]), p[7] - bftrunc(p[7]));
    *(uint2*)&PH[q][g * 4]      = make_uint2(ph0, ph1);
    *(uint2*)&PH[q][16 + g * 4] = make_uint2(ph2, ph3);
    *(uint2*)&PL[q][g * 4]      = make_uint2(pl0, pl1);
    *(uint2*)&PL[q][16 + g * 4] = make_uint2(pl2, pl3);
    const s16x8 Pw  = *(const s16x8*)&PH[q][g * 8];
    const s16x8 Pwl = *(const s16x8*)&PL[q][g * 8];

    // O^T += V^T * P^T  (D[dim][query]); split terms: VhPh + VlPh + VhPl
    Oa = MFMA16(V0h, Pw,  Oa);  Ob = MFMA16(V1h, Pw,  Ob);
    Oa = MFMA16(V0l, Pw,  Oa);  Ob = MFMA16(V1l, Pw,  Ob);
    Oa = MFMA16(V0h, Pwl, Oa);  Ob = MFMA16(V1h, Pwl, Ob);
  }

  // full-row l: sum over the 4 g-groups
  l += __shfl_xor(l, 16);
  l += __shfl_xor(l, 32);
  const float inv = 1.f / fmaxf(l, 1e-30f);

  // Oa: dims g*4..g*4+3; Ob: dims 16+g*4..+3 of query q
  float* op = out + (size_t)(bL + qt * 16 + q) * 256 + h * 32;
  *(float4*)(op + g * 4) =
      make_float4(Oa[0] * inv, Oa[1] * inv, Oa[2] * inv, Oa[3] * inv);
  *(float4*)(op + 16 + g * 4) =
      make_float4(Ob[0] * inv, Ob[1] * inv, Ob[2] * inv, Ob[3] * inv);
}

// ---------------- launch ----------------
extern "C" void kernel_launch(void* const* d_in, const int* in_sizes, int n_in,
                              void* d_out, int out_size, void* d_ws, size_t ws_size,
                              hipStream_t stream) {
  const float* x    = (const float*)d_in[0];
  const float* mask = (const float*)d_in[1];
  const float* Wq   = (const float*)d_in[2];
  const float* Wk   = (const float*)d_in[3];
  const float* Wv   = (const float*)d_in[4];
  const float* Wo   = (const float*)d_in[5];
  const float* W1   = (const float*)d_in[6];
  const float* b1   = (const float*)d_in[7];
  const float* W2   = (const float*)d_in[8];
  const float* b2   = (const float*)d_in[9];
  float* outp = (float*)d_out;

  char* ws = (char*)d_ws;
  float* xc    = (float*)(ws);                        // 8 MiB  [8192][256] f32
  u16*   qh    = (u16*)(ws + ((size_t)8  << 20));     // 12 MiB [8192][768] bf16 hi
  u16*   ql    = (u16*)(ws + ((size_t)20 << 20));     // 12 MiB [8192][768] bf16 lo
  u16*   vth   = (u16*)(ws + ((size_t)32 << 20));     // 4 MiB  [4][8][32][2048] hi
  u16*   vtl   = (u16*)(ws + ((size_t)36 << 20));     // 4 MiB  lo
  float* wqkvT = (float*)(ws + ((size_t)40 << 20));   // 3 MiB  [4][256][768]
  float* ffb   = (float*)(ws + ((size_t)8  << 20));   // 16 MiB, aliases qh/ql (dead)
  float* attno = outp;                                // reuse d_out as scratch

  hipMemcpyAsync(xc, x, (size_t)8192 * 256 * sizeof(float),
                 hipMemcpyDeviceToDevice, stream);
  prep_wqkv_kernel<<<3072, 256, 0, stream>>>(Wq, Wk, Wv, wqkvT);

  for (int n = 0; n < 4; ++n) {
    // 1) qkv (split-bf16 out): [8192,768]
    gemm_f32_kernel<3><<<dim3(64, 12), 256, 0, stream>>>(
        xc, wqkvT + (size_t)n * 256 * 768, nullptr, nullptr, nullptr,
        qh, ql, 8192, 768, 256);
    // 2) V transpose
    vtrans_kernel<<<512, 256, 0, stream>>>(qh, ql, vth, vtl);
    // 3) attention -> attno (d_out)
    attn_mfma_kernel<<<4096, 64, 0, stream>>>(qh, ql, vth, vtl, mask, attno);
    // 4) xc = (attno @ Wo + xc) * 0.5
    gemm_f32_kernel<2><<<dim3(64, 4), 256, 0, stream>>>(
        attno, Wo + (size_t)n * 256 * 256, xc, nullptr, xc, nullptr, nullptr,
        8192, 256, 256);
    // 5) ff = gelu(xc @ W1 + b1)
    gemm_f32_kernel<1><<<dim3(64, 8), 256, 0, stream>>>(
        xc, W1 + (size_t)n * 256 * 512, ffb, b1 + (size_t)n * 512, nullptr,
        nullptr, nullptr, 8192, 512, 256);
    // 6) xc = (ff @ W2 + b2 + xc) * 0.5   (last layer -> d_out)
    gemm_f32_kernel<2><<<dim3(64, 4), 256, 0, stream>>>(
        ffb, W2 + (size_t)n * 512 * 256, (n == 3) ? outp : xc,
        b2 + (size_t)n * 256, xc, nullptr, nullptr, 8192, 256, 512);
  }
}

// Round 8
// 1342.176 us; speedup vs baseline: 2.6759x; 1.1893x over previous
//
#include <hip/hip_runtime.h>
#include <hip/hip_bf16.h>
#include <math.h>

#define NEGF (-3.402823466e38f)

typedef unsigned int u32;
typedef unsigned short u16;
typedef __attribute__((ext_vector_type(8))) short s16x8;
typedef __attribute__((ext_vector_type(4))) float f32x4;

#define MFMA16(a, b, c) __builtin_amdgcn_mfma_f32_16x16x32_bf16(a, b, c, 0, 0, 0)

// pack (low16=trunc-bf16(a), high16=trunc-bf16(b)) into one u32
__device__ __forceinline__ u32 pkhi(float a, float b) {
  return __builtin_amdgcn_perm(__builtin_bit_cast(u32, b),
                               __builtin_bit_cast(u32, a), 0x07060302u);
}
__device__ __forceinline__ float bftrunc(float x) {
  return __builtin_bit_cast(float, __builtin_bit_cast(u32, x) & 0xFFFF0000u);
}
__device__ __forceinline__ u16 hib(float x) {
  return (u16)(__builtin_bit_cast(u32, x) >> 16);
}

// ------------- per-layer weight prep: transpose [K][N] f32 -> [N][K] u16 hi/lo ----
// grid 512 blocks of 256 thr, each transposes one 32x32 tile via LDS.
__global__ __launch_bounds__(256)
void wprep_kernel(const float* __restrict__ Wq, const float* __restrict__ Wk,
                  const float* __restrict__ Wv, const float* __restrict__ Wo,
                  const float* __restrict__ W1, const float* __restrict__ W2,
                  int layer,
                  u16* __restrict__ qkvh, u16* __restrict__ qkvl,
                  u16* __restrict__ woh, u16* __restrict__ wol,
                  u16* __restrict__ w1h, u16* __restrict__ w1l,
                  u16* __restrict__ w2h, u16* __restrict__ w2l) {
  __shared__ float L[32][33];
  const int b = blockIdx.x, t = threadIdx.x;
  const float* src; int spitch; u16 *dh, *dl; int dpitch;
  if (b < 192) {                       // wqkv: per (ty,h): transpose [256 d][32 e]
    int ty = b / 64, rem = b % 64, h = rem >> 3, dt = rem & 7;
    const float* W = (ty == 0) ? Wq : (ty == 1) ? Wk : Wv;
    src = W + (((size_t)layer * 8 + h) * 256 + dt * 32) * 32;
    spitch = 32;
    dh = qkvh + (size_t)(ty * 256 + h * 32) * 256 + dt * 32;
    dl = qkvl + (size_t)(ty * 256 + h * 32) * 256 + dt * 32;
    dpitch = 256;
  } else if (b < 256) {                // wo [256][256]
    int b2 = b - 192, kt = b2 >> 3, nt = b2 & 7;
    src = Wo + (size_t)layer * 65536 + (size_t)(kt * 32) * 256 + nt * 32;
    spitch = 256;
    dh = woh + (size_t)(nt * 32) * 256 + kt * 32;
    dl = wol + (size_t)(nt * 32) * 256 + kt * 32;
    dpitch = 256;
  } else if (b < 384) {                // w1 [256][512]
    int b3 = b - 256, kt = b3 >> 4, nt = b3 & 15;
    src = W1 + (size_t)layer * 131072 + (size_t)(kt * 32) * 512 + nt * 32;
    spitch = 512;
    dh = w1h + (size_t)(nt * 32) * 256 + kt * 32;
    dl = w1l + (size_t)(nt * 32) * 256 + kt * 32;
    dpitch = 256;
  } else {                             // w2 [512][256]
    int b4 = b - 384, kt = b4 >> 3, nt = b4 & 7;
    src = W2 + (size_t)layer * 131072 + (size_t)(kt * 32) * 256 + nt * 32;
    spitch = 256;
    dh = w2h + (size_t)(nt * 32) * 512 + kt * 32;
    dl = w2l + (size_t)(nt * 32) * 512 + kt * 32;
    dpitch = 512;
  }
  {
    int kk = t >> 3, n4 = (t & 7) * 4;
    float4 f = *(const float4*)(src + (size_t)kk * spitch + n4);
    L[kk][n4] = f.x; L[kk][n4 + 1] = f.y; L[kk][n4 + 2] = f.z; L[kk][n4 + 3] = f.w;
  }
  __syncthreads();
  {
    int nn = t >> 3, k4 = (t & 7) * 4;
    float x0 = L[k4][nn], x1 = L[k4 + 1][nn], x2 = L[k4 + 2][nn], x3 = L[k4 + 3][nn];
    *(uint2*)(dh + (size_t)nn * dpitch + k4) = make_uint2(pkhi(x0, x1), pkhi(x2, x3));
    float l0 = x0 - bftrunc(x0), l1 = x1 - bftrunc(x1);
    float l2 = x2 - bftrunc(x2), l3 = x3 - bftrunc(x3);
    *(uint2*)(dl + (size_t)nn * dpitch + k4) = make_uint2(pkhi(l0, l1), pkhi(l2, l3));
  }
}

// ---------------- split-bf16 MFMA GEMM: 128x64 tile, 4 waves, BK=32 ----------------
// AMODE 0: A = f32 (split during staging). AMODE 1: A = u16 hi/lo pair.
// EP 0: split hi/lo out. EP 1: gelu(acc+bias) -> split out. EP 2: (acc[+bias]+res)*0.5 -> f32.
// Fragment maps identical to the round-6-verified attn kernel.
template <int AMODE, int EP>
__global__ __launch_bounds__(256)
void gemm_mfma_kernel(const float* __restrict__ Af,
                      const u16* __restrict__ Ahp, const u16* __restrict__ Alp,
                      const u16* __restrict__ BTh, const u16* __restrict__ BTl,
                      float* __restrict__ Cf, u16* __restrict__ Chp,
                      u16* __restrict__ Clp, const float* __restrict__ bias,
                      const float* __restrict__ res, int M, int N, int K) {
  __shared__ u16 Ah[128][40], Al[128][40], Bh[64][40], Bl[64][40];
  const int t = threadIdx.x;
  const int wave = t >> 6, lane = t & 63;
  const int q = lane & 15, g = lane >> 4;
  const int wr = wave >> 1, wc = wave & 1;
  const int r0 = blockIdx.x * 128, n0 = blockIdx.y * 64;

  f32x4 acc[4][2] = {};

  for (int k0 = 0; k0 < K; k0 += 32) {
    __syncthreads();
    {   // stage A tile [128][32]
      int row = t >> 1, half = t & 1;
      if (AMODE == 0) {
        const float* src = Af + (size_t)(r0 + row) * K + k0 + half * 16;
        float xv[16];
        #pragma unroll
        for (int i = 0; i < 4; ++i) {
          float4 f = *(const float4*)(src + 4 * i);
          xv[4*i] = f.x; xv[4*i+1] = f.y; xv[4*i+2] = f.z; xv[4*i+3] = f.w;
        }
        uint4 H0 = make_uint4(pkhi(xv[0], xv[1]), pkhi(xv[2], xv[3]),
                              pkhi(xv[4], xv[5]), pkhi(xv[6], xv[7]));
        uint4 H1 = make_uint4(pkhi(xv[8], xv[9]), pkhi(xv[10], xv[11]),
                              pkhi(xv[12], xv[13]), pkhi(xv[14], xv[15]));
        float rv[16];
        #pragma unroll
        for (int i = 0; i < 16; ++i) rv[i] = xv[i] - bftrunc(xv[i]);
        uint4 L0 = make_uint4(pkhi(rv[0], rv[1]), pkhi(rv[2], rv[3]),
                              pkhi(rv[4], rv[5]), pkhi(rv[6], rv[7]));
        uint4 L1 = make_uint4(pkhi(rv[8], rv[9]), pkhi(rv[10], rv[11]),
                              pkhi(rv[12], rv[13]), pkhi(rv[14], rv[15]));
        *(uint4*)&Ah[row][half * 16]     = H0;
        *(uint4*)&Ah[row][half * 16 + 8] = H1;
        *(uint4*)&Al[row][half * 16]     = L0;
        *(uint4*)&Al[row][half * 16 + 8] = L1;
      } else {
        const u16* sh = Ahp + (size_t)(r0 + row) * K + k0 + half * 16;
        const u16* sl = Alp + (size_t)(r0 + row) * K + k0 + half * 16;
        *(uint4*)&Ah[row][half * 16]     = *(const uint4*)sh;
        *(uint4*)&Ah[row][half * 16 + 8] = *(const uint4*)(sh + 8);
        *(uint4*)&Al[row][half * 16]     = *(const uint4*)sl;
        *(uint4*)&Al[row][half * 16 + 8] = *(const uint4*)(sl + 8);
      }
    }
    {   // stage B tile [64][32] from BT [N][K]
      int n = t >> 2, seg = t & 3;
      size_t off = (size_t)(n0 + n) * K + k0 + seg * 8;
      *(uint4*)&Bh[n][seg * 8] = *(const uint4*)(BTh + off);
      *(uint4*)&Bl[n][seg * 8] = *(const uint4*)(BTl + off);
    }
    __syncthreads();

    s16x8 afh[4], afl[4], bfh[2], bfl[2];
    #pragma unroll
    for (int mi = 0; mi < 4; ++mi) {
      afh[mi] = *(const s16x8*)&Ah[wr * 64 + mi * 16 + q][g * 8];
      afl[mi] = *(const s16x8*)&Al[wr * 64 + mi * 16 + q][g * 8];
    }
    #pragma unroll
    for (int nj = 0; nj < 2; ++nj) {
      bfh[nj] = *(const s16x8*)&Bh[wc * 32 + nj * 16 + q][g * 8];
      bfl[nj] = *(const s16x8*)&Bl[wc * 32 + nj * 16 + q][g * 8];
    }
    #pragma unroll
    for (int mi = 0; mi < 4; ++mi)
      #pragma unroll
      for (int nj = 0; nj < 2; ++nj) {
        acc[mi][nj] = MFMA16(afh[mi], bfh[nj], acc[mi][nj]);
        acc[mi][nj] = MFMA16(afl[mi], bfh[nj], acc[mi][nj]);
        acc[mi][nj] = MFMA16(afh[mi], bfl[nj], acc[mi][nj]);
      }
  }

  // epilogue: C row = r0 + wr*64 + mi*16 + g*4 + r, col = n0 + wc*32 + nj*16 + q
  #pragma unroll
  for (int mi = 0; mi < 4; ++mi)
    #pragma unroll
    for (int nj = 0; nj < 2; ++nj) {
      const int col = n0 + wc * 32 + nj * 16 + q;
      #pragma unroll
      for (int r = 0; r < 4; ++r) {
        const int row = r0 + wr * 64 + mi * 16 + g * 4 + r;
        const size_t off = (size_t)row * N + col;
        float x = acc[mi][nj][r];
        if (EP == 1) {
          x += bias[col];
          x = 0.5f * x * (1.f + erff(x * 0.70710678118654752f));
        } else if (EP == 2) {
          if (bias) x += bias[col];
          x = (x + res[off]) * 0.5f;
        }
        if (EP == 2) {
          Cf[off] = x;
        } else {
          Chp[off] = hib(x);
          Clp[off] = hib(x - bftrunc(x));
        }
      }
    }
}

// ---------------- V transpose: qh/ql [8192][768] -> vt [b][h][32][2048] bf16 ------
__global__ __launch_bounds__(256)
void vtrans_kernel(const u16* __restrict__ qh, const u16* __restrict__ ql,
                   u16* __restrict__ vth, u16* __restrict__ vtl) {
  __shared__ u16 T[128][36];
  const int wg = blockIdx.x;
  const int tb = wg & 15, h = (wg >> 4) & 7, b = wg >> 7;
  const int t = threadIdx.x;
  const int tok = t >> 1, eo = (t & 1) * 16;
  const int e = t >> 3, seg = t & 7;
  #pragma unroll 1
  for (int pass = 0; pass < 2; ++pass) {
    const u16* src = pass ? ql : qh;
    u16* dst = pass ? vtl : vth;
    if (pass) __syncthreads();
    const u16* p = src + (size_t)(b * 2048 + tb * 128 + tok) * 768 + 512 + h * 32 + eo;
    uint2 u0 = *(const uint2*)p;
    uint2 u1 = *(const uint2*)(p + 4);
    uint2 u2 = *(const uint2*)(p + 8);
    uint2 u3 = *(const uint2*)(p + 12);
    *(uint2*)&T[tok][eo]      = u0;
    *(uint2*)&T[tok][eo + 4]  = u1;
    *(uint2*)&T[tok][eo + 8]  = u2;
    *(uint2*)&T[tok][eo + 12] = u3;
    __syncthreads();
    u32 w[8];
    #pragma unroll
    for (int i = 0; i < 8; ++i) {
      u32 lo16 = T[seg * 16 + 2 * i][e];
      u32 hi16 = T[seg * 16 + 2 * i + 1][e];
      w[i] = lo16 | (hi16 << 16);
    }
    u16* qp = dst + ((size_t)((b * 8 + h) * 32 + e)) * 2048 + tb * 128 + seg * 16;
    *(uint4*)qp       = make_uint4(w[0], w[1], w[2], w[3]);
    *(uint4*)(qp + 8) = make_uint4(w[4], w[5], w[6], w[7]);
  }
}

// ---------------- MFMA flash attention, 64-key tiles, 4 waves/block ----------------
// grid 1024 = qtg*32 + bh; wave handles q-tile qt = qtg*4 + wave (16 queries).
// Deferred rescale (THR=8); all exp args finite & clamped -> NaN impossible.
__global__ __launch_bounds__(256, 4)
void attn_mfma_kernel(const u16* __restrict__ qh, const u16* __restrict__ ql,
                      const u16* __restrict__ vth, const u16* __restrict__ vtl,
                      const float* __restrict__ mask,
                      u16* __restrict__ oh, u16* __restrict__ ol) {
  __shared__ u16 PH[4][16][72];
  __shared__ u16 PL[4][16][72];
  const int wg = blockIdx.x;
  const int bh = wg & 31, qtg = wg >> 5;
  const int b = bh >> 3, h = bh & 7;
  const int bL = b * 2048;
  const int t = threadIdx.x;
  const int wave = t >> 6, lane = t & 63;
  const int q = lane & 15, g = lane >> 4;
  const int qt = qtg * 4 + wave;

  const size_t qoff = (size_t)(bL + qt * 16 + q) * 768 + h * 32 + g * 8;
  const s16x8 Qh  = *(const s16x8*)(qh + qoff);
  const s16x8 Qlo = *(const s16x8*)(ql + qoff);
  const float mq = mask[bL + qt * 16 + q];

  const u16* kb_h = qh + ((size_t)(bL + q) * 768 + 256 + h * 32 + g * 8);
  const u16* kb_l = ql + ((size_t)(bL + q) * 768 + 256 + h * 32 + g * 8);
  const u16* vb_h = vth + (size_t)(bh * 32 + q) * 2048 + g * 8;
  const u16* vb_l = vtl + (size_t)(bh * 32 + q) * 2048 + g * 8;
  const float* mb = mask + bL + lane;

  f32x4 Oa = {}, Ob = {};
  float m = NEGF, l = 0.f;

  #pragma unroll 1
  for (int tt = 0; tt < 32; ++tt) {
    const size_t kof = (size_t)tt * 64 * 768;
    const s16x8 K0h = *(const s16x8*)(kb_h + kof);
    const s16x8 K1h = *(const s16x8*)(kb_h + kof + 16 * 768);
    const s16x8 K2h = *(const s16x8*)(kb_h + kof + 32 * 768);
    const s16x8 K3h = *(const s16x8*)(kb_h + kof + 48 * 768);
    const s16x8 K0l = *(const s16x8*)(kb_l + kof);
    const s16x8 K1l = *(const s16x8*)(kb_l + kof + 16 * 768);
    const s16x8 K2l = *(const s16x8*)(kb_l + kof + 32 * 768);
    const s16x8 K3l = *(const s16x8*)(kb_l + kof + 48 * 768);
    const float mk = mb[tt * 64];

    f32x4 S0 = {}, S1 = {}, S2 = {}, S3 = {};
    S0 = MFMA16(K0h, Qh, S0);  S1 = MFMA16(K1h, Qh, S1);
    S2 = MFMA16(K2h, Qh, S2);  S3 = MFMA16(K3h, Qh, S3);
    S0 = MFMA16(K0l, Qh, S0);  S1 = MFMA16(K1l, Qh, S1);
    S2 = MFMA16(K2l, Qh, S2);  S3 = MFMA16(K3l, Qh, S3);
    S0 = MFMA16(K0h, Qlo, S0); S1 = MFMA16(K1h, Qlo, S1);
    S2 = MFMA16(K2h, Qlo, S2); S3 = MFMA16(K3h, Qlo, S3);

    // V loads issued here: latency hides under softmax
    const int vo = tt * 64;
    const s16x8 Vah  = *(const s16x8*)(vb_h + vo);
    const s16x8 Vbh  = *(const s16x8*)(vb_h + vo + 32);
    const s16x8 V1ah = *(const s16x8*)(vb_h + 16 * 2048 + vo);
    const s16x8 V1bh = *(const s16x8*)(vb_h + 16 * 2048 + vo + 32);
    const s16x8 Val  = *(const s16x8*)(vb_l + vo);
    const s16x8 Vbl  = *(const s16x8*)(vb_l + vo + 32);
    const s16x8 V1al = *(const s16x8*)(vb_l + 16 * 2048 + vo);
    const s16x8 V1bl = *(const s16x8*)(vb_l + 16 * 2048 + vo + 32);

    unsigned long long em = __ballot(mk != 0.f);
    em = (mq != 0.f) ? em : 0ull;
    float p[16];
    #pragma unroll
    for (int r = 0; r < 4; ++r) {
      p[r]      = ((em >> (g * 4 + r)) & 1ull)      ? S0[r] : NEGF;
      p[4 + r]  = ((em >> (16 + g * 4 + r)) & 1ull) ? S1[r] : NEGF;
      p[8 + r]  = ((em >> (32 + g * 4 + r)) & 1ull) ? S2[r] : NEGF;
      p[12 + r] = ((em >> (48 + g * 4 + r)) & 1ull) ? S3[r] : NEGF;
    }
    float mt = fmaxf(fmaxf(fmaxf(p[0], p[1]), fmaxf(p[2], p[3])),
                     fmaxf(fmaxf(p[4], p[5]), fmaxf(p[6], p[7])));
    mt = fmaxf(mt, fmaxf(fmaxf(fmaxf(p[8], p[9]), fmaxf(p[10], p[11])),
                         fmaxf(fmaxf(p[12], p[13]), fmaxf(p[14], p[15]))));
    mt = fmaxf(mt, __shfl_xor(mt, 16));
    mt = fmaxf(mt, __shfl_xor(mt, 32));
    if (__any(mt > m + 8.f)) {        // deferred rescale (rare)
      const float mn = fmaxf(m, mt);
      const float rr = __expf(m - mn);   // finite args, <= 0
      l *= rr;
      #pragma unroll
      for (int r = 0; r < 4; ++r) { Oa[r] *= rr; Ob[r] *= rr; }
      m = mn;
    }
    #pragma unroll
    for (int j = 0; j < 16; ++j) p[j] = __expf(fminf(p[j] - m, 60.f)); // <= e^8
    l += (((p[0] + p[1]) + (p[2] + p[3])) + ((p[4] + p[5]) + (p[6] + p[7])))
       + (((p[8] + p[9]) + (p[10] + p[11])) + ((p[12] + p[13]) + (p[14] + p[15])));

    #pragma unroll
    for (int i = 0; i < 4; ++i) {
      float a0 = p[4*i], a1 = p[4*i+1], a2 = p[4*i+2], a3 = p[4*i+3];
      *(uint2*)&PH[wave][q][i * 16 + g * 4] =
          make_uint2(pkhi(a0, a1), pkhi(a2, a3));
      float l0 = a0 - bftrunc(a0), l1 = a1 - bftrunc(a1);
      float l2 = a2 - bftrunc(a2), l3 = a3 - bftrunc(a3);
      *(uint2*)&PL[wave][q][i * 16 + g * 4] =
          make_uint2(pkhi(l0, l1), pkhi(l2, l3));
    }
    const s16x8 Pah = *(const s16x8*)&PH[wave][q][g * 8];
    const s16x8 Pbh = *(const s16x8*)&PH[wave][q][32 + g * 8];
    const s16x8 Pal = *(const s16x8*)&PL[wave][q][g * 8];
    const s16x8 Pbl = *(const s16x8*)&PL[wave][q][32 + g * 8];

    Oa = MFMA16(Vah, Pah, Oa);  Oa = MFMA16(Val, Pah, Oa);  Oa = MFMA16(Vah, Pal, Oa);
    Oa = MFMA16(Vbh, Pbh, Oa);  Oa = MFMA16(Vbl, Pbh, Oa);  Oa = MFMA16(Vbh, Pbl, Oa);
    Ob = MFMA16(V1ah, Pah, Ob); Ob = MFMA16(V1al, Pah, Ob); Ob = MFMA16(V1ah, Pal, Ob);
    Ob = MFMA16(V1bh, Pbh, Ob); Ob = MFMA16(V1bl, Pbh, Ob); Ob = MFMA16(V1bh, Pbl, Ob);
  }

  l += __shfl_xor(l, 16);
  l += __shfl_xor(l, 32);
  const float inv = 1.f / fmaxf(l, 1e-30f);

  const size_t ob = (size_t)(bL + qt * 16 + q) * 256 + h * 32;
  float a0 = Oa[0] * inv, a1 = Oa[1] * inv, a2 = Oa[2] * inv, a3 = Oa[3] * inv;
  float b0 = Ob[0] * inv, b1 = Ob[1] * inv, b2 = Ob[2] * inv, b3 = Ob[3] * inv;
  *(uint2*)&oh[ob + g * 4]      = make_uint2(pkhi(a0, a1), pkhi(a2, a3));
  *(uint2*)&oh[ob + 16 + g * 4] = make_uint2(pkhi(b0, b1), pkhi(b2, b3));
  float ra0 = a0 - bftrunc(a0), ra1 = a1 - bftrunc(a1);
  float ra2 = a2 - bftrunc(a2), ra3 = a3 - bftrunc(a3);
  float rb0 = b0 - bftrunc(b0), rb1 = b1 - bftrunc(b1);
  float rb2 = b2 - bftrunc(b2), rb3 = b3 - bftrunc(b3);
  *(uint2*)&ol[ob + g * 4]      = make_uint2(pkhi(ra0, ra1), pkhi(ra2, ra3));
  *(uint2*)&ol[ob + 16 + g * 4] = make_uint2(pkhi(rb0, rb1), pkhi(rb2, rb3));
}

// ---------------- launch ----------------
extern "C" void kernel_launch(void* const* d_in, const int* in_sizes, int n_in,
                              void* d_out, int out_size, void* d_ws, size_t ws_size,
                              hipStream_t stream) {
  const float* x    = (const float*)d_in[0];
  const float* mask = (const float*)d_in[1];
  const float* Wq   = (const float*)d_in[2];
  const float* Wk   = (const float*)d_in[3];
  const float* Wv   = (const float*)d_in[4];
  const float* Wo   = (const float*)d_in[5];
  const float* W1   = (const float*)d_in[6];
  const float* b1   = (const float*)d_in[7];
  const float* W2   = (const float*)d_in[8];
  const float* b2   = (const float*)d_in[9];
  float* outp = (float*)d_out;

  char* ws = (char*)d_ws;
  float* xc  = (float*)(ws);                          //  8 MiB [8192][256] f32
  u16*   qh  = (u16*)(ws + ((size_t)8  << 20));       // 12 MiB [8192][768] hi
  u16*   ql  = (u16*)(ws + ((size_t)20 << 20));       // 12 MiB [8192][768] lo
  u16*   vth = (u16*)(ws + ((size_t)32 << 20));       //  4 MiB
  u16*   vtl = (u16*)(ws + ((size_t)36 << 20));       //  4 MiB
  // per-layer split weights (2.125 MiB region at 40 MiB)
  char* wb = ws + ((size_t)40 << 20);
  u16* qkvTh = (u16*)(wb);                            // 384 KiB [768][256]
  u16* qkvTl = (u16*)(wb + 393216);
  u16* woTh  = (u16*)(wb + 786432);                   // 128 KiB [256][256]
  u16* woTl  = (u16*)(wb + 917504);
  u16* w1Th  = (u16*)(wb + 1048576);                  // 256 KiB [512][256]
  u16* w1Tl  = (u16*)(wb + 1310720);
  u16* w2Th  = (u16*)(wb + 1572864);                  // 256 KiB [256][512]
  u16* w2Tl  = (u16*)(wb + 1835008);
  // ff split aliases qh/ql regions (dead after attn)
  u16* ffh = qh;                                      //  8 MiB [8192][512]
  u16* ffl = ql;
  // attn output split lives in d_out (dead before final write)
  u16* attnoh = (u16*)d_out;                          //  4 MiB [8192][256]
  u16* attnol = attnoh + (size_t)8192 * 256;

  hipMemcpyAsync(xc, x, (size_t)8192 * 256 * sizeof(float),
                 hipMemcpyDeviceToDevice, stream);

  for (int n = 0; n < 4; ++n) {
    wprep_kernel<<<512, 256, 0, stream>>>(Wq, Wk, Wv, Wo, W1, W2, n,
                                          qkvTh, qkvTl, woTh, woTl,
                                          w1Th, w1Tl, w2Th, w2Tl);
    // 1) qkv = xc @ Wqkv  -> split [8192][768]
    gemm_mfma_kernel<0, 0><<<dim3(64, 12), 256, 0, stream>>>(
        xc, nullptr, nullptr, qkvTh, qkvTl, nullptr, qh, ql,
        nullptr, nullptr, 8192, 768, 256);
    // 2) V transpose
    vtrans_kernel<<<512, 256, 0, stream>>>(qh, ql, vth, vtl);
    // 3) attention -> split attno (in d_out)
    attn_mfma_kernel<<<1024, 256, 0, stream>>>(qh, ql, vth, vtl, mask,
                                               attnoh, attnol);
    // 4) xc = (attno @ Wo + xc) * 0.5   (f32)
    gemm_mfma_kernel<1, 2><<<dim3(64, 4), 256, 0, stream>>>(
        nullptr, attnoh, attnol, woTh, woTl, xc, nullptr, nullptr,
        nullptr, xc, 8192, 256, 256);
    // 5) ff = gelu(xc @ W1 + b1) -> split [8192][512]
    gemm_mfma_kernel<0, 1><<<dim3(64, 8), 256, 0, stream>>>(
        xc, nullptr, nullptr, w1Th, w1Tl, nullptr, ffh, ffl,
        b1 + (size_t)n * 512, nullptr, 8192, 512, 256);
    // 6) xc = (ff @ W2 + b2 + xc) * 0.5  (last layer -> d_out)
    gemm_mfma_kernel<1, 2><<<dim3(64, 4), 256, 0, stream>>>(
        nullptr, ffh, ffl, w2Th, w2Tl, (n == 3) ? outp : xc, nullptr, nullptr,
        b2 + (size_t)n * 256, xc, 8192, 256, 512);
  }
}